// Round 9
// baseline (8568.478 us; speedup 1.0000x reference)
//
#include <hip/hip_runtime.h>
#include <hip/hip_bf16.h>
#include <cstddef>

// ---------------------------------------------------------------------------
// Round 9: r8 skeleton (audited) with provable coherence mechanics.
// FAST (same-XCD group): plain stores (write-through -> XCD L2) + vmcnt drain;
//   polls/stages use buffer_inv (L1-only) + volatile loads. No sc-bit bets.
// SLOW (fallback): __hip_atomic relaxed agent ops (round-7-proven).
// All spins watchdog-bounded: failures finish with diagnostic absmax.
// ---------------------------------------------------------------------------

typedef __attribute__((ext_vector_type(8))) __bf16 bf16x8;
typedef __attribute__((ext_vector_type(8))) short s16x8;
typedef __attribute__((ext_vector_type(4))) float f32x4;
typedef unsigned long long u64;
typedef unsigned int u32;

static constexpr int C_BLK = 16;

// ---- ws layout (bytes) ----
static constexpr size_t WS_WG = 0;
static constexpr size_t WS_WH = 4194304;
static constexpr size_t WS_WO = 5767168;
static constexpr size_t WS_BNF = 6045696;
static constexpr size_t WS_BCM = 6053888;
static constexpr size_t WS_BH = 6062080;
static constexpr size_t WS_BO = 6068224;
static constexpr size_t WS_BAR = 6070272;   // 16 * 128B central counters (init only)
static constexpr size_t WS_OFFS = 6072320;  // int[512]
static constexpr size_t WS_FLG = 6074368;   // 16 groups * 1024B: hfl[64] tfl[96] xcc[16]
static constexpr size_t WS_GRP = 6596608;   // 16 * GRPB
static constexpr size_t GRPB = 98304;
// group-internal offsets in SHORTS
static constexpr int TH1_O = 16384;
static constexpr int TH2_O = 32768;
static constexpr int OFFT_O = 40960;

// ---- dynamic LDS (bytes) ----
static constexpr int SM_HB = 0;
static constexpr int SM_T1 = 16384;
static constexpr int SM_TS = 32768;
static constexpr int SM_WH = 49152;
static constexpr int SM_GA = 147456;  // f32 gacc (ga*32+ul)*17+m
static constexpr int SM_OF = 156160;  // offs int[512]
static constexpr int SM_LN = 158208;  // lens int[16]
static constexpr int SM_XC = 158272;  // xcc int[16] + pad
static constexpr int SM_SZ = 158400;

static constexpr int WDOG = 1 << 16;  // poll watchdog iterations

__device__ __forceinline__ unsigned short f2bf(float v) {
  __hip_bfloat16 h = __float2bfloat16(v);
  return *reinterpret_cast<unsigned short*>(&h);
}
__device__ __forceinline__ f32x4 mfma16(s16x8 a, s16x8 b, f32x4 c) {
  return __builtin_amdgcn_mfma_f32_16x16x32_bf16(
      __builtin_bit_cast(bf16x8, a), __builtin_bit_cast(bf16x8, b), c, 0, 0, 0);
}
__device__ __forceinline__ s16x8 ld8(const short* p) { return *(const s16x8*)p; }
__device__ __forceinline__ float sigm(float x) { return 1.0f / (1.0f + expf(-x)); }
__device__ __forceinline__ s16x8 ldA(const char* base, int row, int kb) {
  return *(const s16x8*)(base + row * 1024 + (kb ^ ((row & 7) << 4)));
}
__device__ __forceinline__ void l1inv() { asm volatile("buffer_inv" ::: "memory"); }
#define DRAIN_VM asm volatile("s_waitcnt vmcnt(0)" ::: "memory")

// coherent helpers: FAST = same-XCD (plain + L1-inv), SLOW = agent atomics
template <bool FAST> __device__ __forceinline__ u32 flag_ld(const u32* p) {
  if constexpr (FAST) {
    l1inv();
    return *(volatile const u32*)p;
  } else {
    return __hip_atomic_load(p, __ATOMIC_RELAXED, __HIP_MEMORY_SCOPE_AGENT);
  }
}
template <bool FAST> __device__ __forceinline__ void u32_st(u32* p, u32 v) {
  if constexpr (FAST) *(volatile u32*)p = v;
  else __hip_atomic_store(p, v, __ATOMIC_RELAXED, __HIP_MEMORY_SCOPE_AGENT);
}
template <bool FAST> __device__ __forceinline__ u64 u64_ld(const u64* p) {
  if constexpr (FAST) return *(volatile const u64*)p;
  else return __hip_atomic_load(p, __ATOMIC_RELAXED, __HIP_MEMORY_SCOPE_AGENT);
}

// ---------------- prep: bf16 fragment-order weights (validated) ---------------
__global__ void prep_w(const float* __restrict__ Whh, const float* __restrict__ Wih,
                       const float* __restrict__ p1W2, const float* __restrict__ p1W1,
                       const float* __restrict__ p2W1, const float* __restrict__ offW1,
                       const float* __restrict__ p2W2, const float* __restrict__ offW2,
                       char* __restrict__ ws) {
  int s = blockIdx.x * 256 + threadIdx.x;
  if (s < 262144) {
    int tile = s >> 11, rem = s & 2047;
    int kc = rem >> 6, lane = rem & 63;
    int n = tile * 16 + (lane & 15);
    int k0 = kc * 32 + ((lane >> 4) << 3);
    s16x8 o;
    if (kc < 16) {
      const float* src = Whh + (size_t)n * 512 + k0;
      for (int i = 0; i < 8; i++) o[i] = (short)f2bf(src[i]);
    } else {
      int c0 = k0 - 512;
      float acc[8] = {0, 0, 0, 0, 0, 0, 0, 0};
      const float* wr = Wih + (size_t)n * 128;
      for (int j = 0; j < 128; j++) {
        float wij = wr[j];
        const float* pr = p1W2 + (size_t)j * 512 + c0;
        for (int i = 0; i < 8; i++) acc[i] += wij * pr[i];
      }
      for (int i = 0; i < 8; i++) o[i] = (short)f2bf(acc[i]);
    }
    *(s16x8*)((short*)(ws + WS_WG) + (size_t)(tile * 32 + kc) * 512 + lane * 8) = o;
  } else if (s < 262144 + 98304) {
    int z = s - 262144;
    int tile = z >> 10, rem = z & 1023;
    int kc = rem >> 6, lane = rem & 63;
    int n = tile * 16 + (lane & 15);
    int k0 = kc * 32 + ((lane >> 4) << 3);
    const float* src = (n < 512) ? p1W1 + (size_t)n * 512
                     : (n < 1024) ? p2W1 + (size_t)(n - 512) * 512
                                  : offW1 + (size_t)(n - 1024) * 512;
    s16x8 o;
    for (int i = 0; i < 8; i++) o[i] = (short)f2bf(src[k0 + i]);
    *(s16x8*)((short*)(ws + WS_WH) + (size_t)(tile * 16 + kc) * 512 + lane * 8) = o;
  } else if (s < 262144 + 98304 + 17408) {
    int z = s - 262144 - 98304;
    int tile = z >> 10, rem = z & 1023;
    int kc = rem >> 6, lane = rem & 63;
    int n = tile * 16 + (lane & 15);
    int k0 = kc * 32 + ((lane >> 4) << 3);
    s16x8 o;
    for (int i = 0; i < 8; i++) {
      int k = k0 + i;
      float v = (n < 128) ? p1W2[(size_t)n * 512 + k]
              : (n < 256) ? p2W2[(size_t)(n - 128) * 512 + k]
              : (n == 256) ? offW2[k] : 0.f;
      o[i] = (short)f2bf(v);
    }
    *(s16x8*)((short*)(ws + WS_WO) + (size_t)(tile * 16 + kc) * 512 + lane * 8) = o;
  }
}

// ---------------- prep: biases, counters, offs, flags -------------------------
__global__ void prep_misc(const float* __restrict__ b_ih, const float* __restrict__ b_hh,
                          const float* __restrict__ Wih, const float* __restrict__ p1b2,
                          const float* __restrict__ p1b1, const float* __restrict__ p2b1,
                          const float* __restrict__ offb1, const float* __restrict__ p2b2,
                          const float* __restrict__ offb2, const int* __restrict__ lens,
                          char* __restrict__ ws) {
  int i = blockIdx.x * 256 + threadIdx.x;
  if (i < 2048) {
    float bn = b_ih[i] + b_hh[i];
    ((float*)(ws + WS_BNF))[i] = bn;
    float acc = 0.f;
    const float* wr = Wih + (size_t)i * 128;
    for (int j = 0; j < 128; j++) acc += wr[j] * p1b2[j];
    ((float*)(ws + WS_BCM))[i] = bn + acc;
  } else if (i < 3584) {
    int j = i - 2048;
    ((float*)(ws + WS_BH))[j] =
        j < 512 ? p1b1[j] : (j < 1024 ? p2b1[j - 512] : offb1[j - 1024]);
  } else if (i < 3856) {
    int j = i - 3584;
    ((float*)(ws + WS_BO))[j] =
        j < 128 ? p1b2[j] : (j < 256 ? p2b2[j - 128] : (j == 256 ? offb2[0] : 0.f));
  } else if (i < 3872) {
    *(int*)(ws + WS_BAR + (size_t)(i - 3856) * 128) = 0;
  } else if (i < 4384) {
    int t = i - 3872;
    int s = 0;
    for (int b = 0; b < 256; b++) { int L = lens[b]; s += (L < t ? L : t); }
    ((int*)(ws + WS_OFFS))[t] = s;
  } else if (i < 4384 + 4096) {
    ((u32*)(ws + WS_FLG))[i - 4384] = 0;
  }
}

// ---------------- main persistent kernel -------------------------------------
struct TagFast { static constexpr bool fast = true; };
struct TagSlow { static constexpr bool fast = false; };

__launch_bounds__(512, 2)
__global__ void rnn_main(const float* __restrict__ features, const float* __restrict__ Wf2h,
                         const float* __restrict__ bf2h, const int* __restrict__ lens,
                         char* __restrict__ ws, float* __restrict__ out, int N) {
  extern __shared__ char sm[];
  const int g = blockIdx.x & 15;
  const int rank = blockIdx.x >> 4;
  const int tid = threadIdx.x, w = tid >> 6, l = tid & 63, lr = l & 15, hi = l >> 4;

  const short* Wg = (const short*)(ws + WS_WG);
  const short* Wh = (const short*)(ws + WS_WH);
  const short* Wo = (const short*)(ws + WS_WO);
  const float* bnf = (const float*)(ws + WS_BNF);
  const float* bcm = (const float*)(ws + WS_BCM);
  const float* bh = (const float*)(ws + WS_BH);
  const float* bo = (const float*)(ws + WS_BO);
  const int* offs_g = (const int*)(ws + WS_OFFS);
  int* cnt = (int*)(ws + WS_BAR + (size_t)g * 128);
  u32* hfl = (u32*)(ws + WS_FLG + (size_t)g * 1024);
  u32* tfl = hfl + 64;
  u32* xcc_tab = hfl + 160;
  short* hb_ = (short*)(ws + WS_GRP + (size_t)g * GRPB);
  short* t1b = hb_ + TH1_O;
  short* t2b = hb_ + TH2_O;
  short* tob = hb_ + OFFT_O;

  int* lens_s = (int*)(sm + SM_LN);
  int* offs_s = (int*)(sm + SM_OF);
  int* xcc_s = (int*)(sm + SM_XC);
  float* gacc = (float*)(sm + SM_GA);  // idx (ga*32+ul)*17 + m

  if (tid < 16) lens_s[tid] = lens[g * 16 + tid];
  offs_s[tid] = offs_g[tid];

  // stage Wh slice into LDS (once)
  for (int i = tid; i < 6144; i += 512) {
    int lt = i >> 10, c = i & 1023;
    int sec = lt >> 1, j = lt & 1;
    int T = sec * 32 + rank * 2 + j;
    *(s16x8*)(sm + SM_WH + (size_t)i * 16) = ld8(Wh + (size_t)T * 8192 + (size_t)c * 8);
  }

  // ---- init: h0/c0 (tid<256, 2 adjacent units each), publish agent-scope ----
  const int m_c = tid >> 4, p_c = tid & 15;
  const int u0 = rank * 32 + 2 * p_c;
  float creg0 = 0.f, creg1 = 0.f;
  float bn0[4], bn1[4], bc0[4], bc1[4];
  if (tid < 256) {
    const float* fr = features + (size_t)(g * 16 + m_c) * 256;
    const float* wa = Wf2h + (size_t)(2 * u0) * 256;
    float ah0 = 0.f, ac0 = 0.f, ah1 = 0.f, ac1 = 0.f;
    for (int k = 0; k < 256; k++) {
      float fv = fr[k];
      ah0 += fv * wa[k];
      ac0 += fv * wa[256 + k];
      ah1 += fv * wa[512 + k];
      ac1 += fv * wa[768 + k];
    }
    ah0 += bf2h[2 * u0];     ac0 += bf2h[2 * u0 + 1];
    ah1 += bf2h[2 * u0 + 2]; ac1 += bf2h[2 * u0 + 3];
    creg0 = ac0; creg1 = ac1;
    u32 pk = (u32)f2bf(ah0) | ((u32)f2bf(ah1) << 16);
    u32_st<false>((u32*)hb_ + m_c * 256 + rank * 16 + p_c, pk);  // buffer 0, MALL
    for (int ga = 0; ga < 4; ga++) {
      bn0[ga] = bnf[ga * 512 + u0];     bn1[ga] = bnf[ga * 512 + u0 + 1];
      bc0[ga] = bcm[ga * 512 + u0];     bc1[ga] = bcm[ga * 512 + u0 + 1];
    }
  }
  int myxcc;
  asm volatile("s_getreg_b32 %0, hwreg(HW_REG_XCC_ID)" : "=s"(myxcc));
  if (tid == 0) u32_st<false>(xcc_tab + rank, (u32)myxcc);

  // P1 wave constants + gates weights
  const int ga_w = w & 3, j0_w = w >> 2;
  const int tileG = ga_w * 32 + rank * 2 + j0_w;
  s16x8 wgr[32];
  {
    const short* wb = Wg + (size_t)tileG * 16384 + l * 8;
#pragma unroll
    for (int kc = 0; kc < 32; ++kc) wgr[kc] = ld8(wb + (size_t)kc * 512);
  }
  const int secw = w >> 1;
  const int T2 = secw * 32 + rank * 2 + (w & 1);
  const int lt2 = secw * 2 + (w & 1);
  float bh_r = (w < 6) ? bh[T2 * 16 + lr] : 0.f;
  float bo_r = (w == 4) ? bo[rank * 16 + lr] : ((w == 5 && rank == 7) ? bo[256] : 0.f);

  DRAIN_VM;
  __syncthreads();
  int steps = 0;
  for (int i = 0; i < 16; i++) steps = max(steps, lens_s[i]);

  // central agent-scope barrier (watchdog-bounded): h0 + xcc published
  if (tid == 0) {
    __hip_atomic_fetch_add(cnt, 1, __ATOMIC_RELAXED, __HIP_MEMORY_SCOPE_AGENT);
    int wd = 0;
    while (__hip_atomic_load(cnt, __ATOMIC_RELAXED, __HIP_MEMORY_SCOPE_AGENT) < C_BLK &&
           ++wd < (1 << 20))
      __builtin_amdgcn_s_sleep(1);
  }
  __syncthreads();

  if (tid < 16) xcc_s[tid] = (int)flag_ld<false>(xcc_tab + tid);
  __syncthreads();
  bool fast = true;
  for (int i = 0; i < 16; i++) fast = fast && (xcc_s[i] == myxcc);

  const size_t base1 = (size_t)N * 128;
  const size_t base2 = 2 * base1;
  const size_t base3 = base2 + (size_t)N;

  // staging geometry
  const int j0c = tid, j1c = tid + 512;
  const int r0 = j0c >> 6, k0b = (j0c & 63) << 4;
  const int r1 = j1c >> 6, k1b = (j1c & 63) << 4;
  char* d0h = sm + SM_HB + r0 * 1024 + (k0b ^ ((r0 & 7) << 4));
  char* d1h = sm + SM_HB + r1 * 1024 + (k1b ^ ((r1 & 7) << 4));
  char* d0t = sm + SM_T1 + r0 * 1024 + (k0b ^ ((r0 & 7) << 4));
  char* d1t = sm + SM_T1 + r1 * 1024 + (k1b ^ ((r1 & 7) << 4));
  char* d0s = sm + SM_TS + r0 * 1024 + (k0b ^ ((r0 & 7) << 4));
  char* d1s = sm + SM_TS + r1 * 1024 + (k1b ^ ((r1 & 7) << 4));

  // doP3(tt): p1/p2 (wave 4) + offsets (wave 5, rank 7); reads SM_T1/SM_TS
  auto doP3 = [&](int tt) {
    if (tt < 0) return;
    const int offs_t = offs_s[tt];
    if (w == 4) {
      s16x8 wo[16];
      const short* wb = Wo + (size_t)(rank * 16) * 512 + l * 8;
#pragma unroll
      for (int kc = 0; kc < 16; ++kc) wo[kc] = ld8(wb + (size_t)kc * 512);
      f32x4 acc = {0.f, 0.f, 0.f, 0.f};
      const char* ab = sm + (rank < 8 ? SM_T1 : SM_TS);
#pragma unroll
      for (int kc = 0; kc < 16; ++kc)
        acc = mfma16(ldA(ab, lr, kc * 64 + hi * 16), wo[kc], acc);
      const int nW = rank * 16 + lr;
      for (int r = 0; r < 4; r++) {
        int m = hi * 4 + r;
        if (tt < lens_s[m]) {
          size_t pos = (size_t)(offs_t + g * 16 + m);
          float v = acc[r] + bo_r;
          if (rank < 8) {
            out[pos * 128 + nW] = v;
            out[base3 + pos * 128 + nW] = v;
          } else {
            out[base1 + pos * 128 + (nW - 128)] = v;
          }
        }
      }
    } else if (w == 5 && rank == 7) {
      s16x8 wo[16];
      const short* wb = Wo + (size_t)(16 * 16) * 512 + l * 8;
#pragma unroll
      for (int kc = 0; kc < 16; ++kc) wo[kc] = ld8(wb + (size_t)kc * 512);
      f32x4 acc = {0.f, 0.f, 0.f, 0.f};
#pragma unroll
      for (int kc = 0; kc < 16; ++kc)
        acc = mfma16(ldA(sm + SM_TS, lr, kc * 64 + hi * 16), wo[kc], acc);
      if (lr == 0) {
        for (int r = 0; r < 4; r++) {
          int m = hi * 4 + r;
          if (tt < lens_s[m])
            out[base2 + (size_t)(offs_t + g * 16 + m)] = acc[r] + bo_r;
        }
      }
    }
  };

  // prologue: stage SM_HB = h0 (agent loads), SM_T1 = 0
  {
    const u64* hq = (const u64*)hb_;
    u64 a = u64_ld<false>(hq + 2 * j0c), b = u64_ld<false>(hq + 2 * j0c + 1);
    u64 c = u64_ld<false>(hq + 2 * j1c), d = u64_ld<false>(hq + 2 * j1c + 1);
    *(u64*)d0h = a; *(u64*)(d0h + 8) = b;
    *(u64*)d1h = c; *(u64*)(d1h + 8) = d;
    *(u64*)d0t = 0ull; *(u64*)(d0t + 8) = 0ull;
    *(u64*)d1t = 0ull; *(u64*)(d1t + 8) = 0ull;
  }
  __syncthreads();
  f32x4 accP1 = {0.f, 0.f, 0.f, 0.f};
#pragma unroll
  for (int kc = 0; kc < 16; ++kc)
    accP1 = mfma16(ldA(sm + SM_HB, lr, kc * 64 + hi * 16), wgr[kc], accP1);

  auto runloop = [&](auto tag) {
    constexpr bool FAST = decltype(tag)::fast;
    for (int t = 0; t < steps; ++t) {
      const int bufp = (t & 1) ^ 1;  // write parity

      // ---- A: P1 finish (th1(t-1) half) ----
      {
        f32x4 acc = accP1;
#pragma unroll
        for (int kc = 0; kc < 16; ++kc)
          acc = mfma16(ldA(sm + SM_T1, lr, kc * 64 + hi * 16), wgr[16 + kc], acc);
        for (int r = 0; r < 4; r++)
          gacc[(ga_w * 32 + j0_w * 16 + lr) * 17 + hi * 4 + r] = acc[r];
      }
      __syncthreads();  // S1

      // ---- B: cell+publish (w<4) | doP3(t-1) (w4,5) | poll h-flags (w7) ----
      if (w < 4) {
        const int ua = 2 * p_c;
        float gi0 = gacc[(0 * 32 + ua) * 17 + m_c] + (t ? bc0[0] : bn0[0]);
        float gf0 = gacc[(1 * 32 + ua) * 17 + m_c] + (t ? bc0[1] : bn0[1]);
        float gg0 = gacc[(2 * 32 + ua) * 17 + m_c] + (t ? bc0[2] : bn0[2]);
        float go0 = gacc[(3 * 32 + ua) * 17 + m_c] + (t ? bc0[3] : bn0[3]);
        float gi1 = gacc[(0 * 32 + ua + 1) * 17 + m_c] + (t ? bc1[0] : bn1[0]);
        float gf1 = gacc[(1 * 32 + ua + 1) * 17 + m_c] + (t ? bc1[1] : bn1[1]);
        float gg1 = gacc[(2 * 32 + ua + 1) * 17 + m_c] + (t ? bc1[2] : bn1[2]);
        float go1 = gacc[(3 * 32 + ua + 1) * 17 + m_c] + (t ? bc1[3] : bn1[3]);
        float c0 = sigm(gf0) * creg0 + sigm(gi0) * tanhf(gg0);
        float c1 = sigm(gf1) * creg1 + sigm(gi1) * tanhf(gg1);
        creg0 = c0; creg1 = c1;
        float h0v = sigm(go0) * tanhf(c0);
        float h1v = sigm(go1) * tanhf(c1);
        u32 pk = (u32)f2bf(h0v) | ((u32)f2bf(h1v) << 16);
        u32_st<FAST>((u32*)hb_ + bufp * 4096 + m_c * 256 + rank * 16 + p_c, pk);
        DRAIN_VM;
        if (l == 0) u32_st<FAST>(hfl + rank * 4 + w, (u32)(t + 1));
      } else if (w == 4 || w == 5) {
        doP3(t - 1);
      } else if (w == 7) {
        const u32* fp = hfl + l;
        u32 v;
        int wd = 0;
        do { v = flag_ld<FAST>(fp); } while ((int)v < t + 1 && ++wd < WDOG);
      }
      __syncthreads();  // S2

      // ---- C: stage h(t) -> SM_HB ----
      {
        const u64* hq = (const u64*)hb_ + (size_t)bufp * 2048;
        u64 a = u64_ld<FAST>(hq + 2 * j0c), b = u64_ld<FAST>(hq + 2 * j0c + 1);
        u64 c = u64_ld<FAST>(hq + 2 * j1c), d = u64_ld<FAST>(hq + 2 * j1c + 1);
        *(u64*)d0h = a; *(u64*)(d0h + 8) = b;
        *(u64*)d1h = c; *(u64*)(d1h + 8) = d;
      }
      __syncthreads();  // S3

      // ---- D: P2+publish (w<6) | accP1 + poll th-flags (w6,7) ----
      if (w < 6) {
        f32x4 acc = {0.f, 0.f, 0.f, 0.f};
        const char* wl = sm + SM_WH + lt2 * 16384 + l * 16;
#pragma unroll
        for (int kc = 0; kc < 16; ++kc)
          acc = mfma16(ldA(sm + SM_HB, lr, kc * 64 + hi * 16),
                       *(const s16x8*)(wl + kc * 1024), acc);
        u32 my[4];
        for (int r = 0; r < 4; r++) my[r] = (u32)f2bf(tanhf(acc[r] + bh_r));
        u32 wordv[4];
        for (int r = 0; r < 4; r++) {
          u32 oth = (u32)__shfl_xor((int)my[r], 1, 64);
          wordv[r] = my[r] | (oth << 16);
        }
        if (!(l & 1)) {
          const int cp = lr >> 1;
          for (int r = 0; r < 4; r++) {
            int m = hi * 4 + r;
            u32* dst = (T2 < 32) ? (u32*)t1b + bufp * 4096 + m * 256 + T2 * 8 + cp
                     : (T2 < 64) ? (u32*)t2b + m * 256 + (T2 - 32) * 8 + cp
                                 : (u32*)tob + m * 256 + (T2 - 64) * 8 + cp;
            u32_st<FAST>(dst, wordv[r]);
          }
        }
        DRAIN_VM;
        if (l == 0) u32_st<FAST>(tfl + rank * 6 + w, (u32)(t + 1));
        f32x4 ap = {0.f, 0.f, 0.f, 0.f};
#pragma unroll
        for (int kc = 0; kc < 16; ++kc)
          ap = mfma16(ldA(sm + SM_HB, lr, kc * 64 + hi * 16), wgr[kc], ap);
        accP1 = ap;
      } else {
        f32x4 ap = {0.f, 0.f, 0.f, 0.f};
#pragma unroll
        for (int kc = 0; kc < 16; ++kc)
          ap = mfma16(ldA(sm + SM_HB, lr, kc * 64 + hi * 16), wgr[kc], ap);
        accP1 = ap;
        if (l < 48) {
          const u32* fp = tfl + ((w == 6) ? l : 48 + l);
          u32 v;
          int wd = 0;
          do { v = flag_ld<FAST>(fp); } while ((int)v < t + 1 && ++wd < WDOG);
        }
      }
      __syncthreads();  // S4

      // ---- E: stage th1(t) -> SM_T1 (+ th2/tob -> SM_TS for ranks>=7) ----
      {
        const u64* tq = (const u64*)t1b + (size_t)bufp * 2048;
        u64 a = u64_ld<FAST>(tq + 2 * j0c), b = u64_ld<FAST>(tq + 2 * j0c + 1);
        u64 c = u64_ld<FAST>(tq + 2 * j1c), d = u64_ld<FAST>(tq + 2 * j1c + 1);
        *(u64*)d0t = a; *(u64*)(d0t + 8) = b;
        *(u64*)d1t = c; *(u64*)(d1t + 8) = d;
        if (rank >= 7) {
          const u64* sq = (const u64*)(rank == 7 ? tob : t2b);
          u64 e = u64_ld<FAST>(sq + 2 * j0c), f2 = u64_ld<FAST>(sq + 2 * j0c + 1);
          u64 gq = u64_ld<FAST>(sq + 2 * j1c), h2 = u64_ld<FAST>(sq + 2 * j1c + 1);
          *(u64*)d0s = e; *(u64*)(d0s + 8) = f2;
          *(u64*)d1s = gq; *(u64*)(d1s + 8) = h2;
        }
      }
      __syncthreads();  // S5
    }
  };

  if (fast) runloop(TagFast{});
  else runloop(TagSlow{});

  doP3(steps - 1);
}

extern "C" void kernel_launch(void* const* d_in, const int* in_sizes, int n_in,
                              void* d_out, int out_size, void* d_ws, size_t ws_size,
                              hipStream_t stream) {
  const float* features = (const float*)d_in[0];
  const float* W_f2h = (const float*)d_in[1];
  const float* b_f2h = (const float*)d_in[2];
  const float* W_ih = (const float*)d_in[3];
  const float* W_hh = (const float*)d_in[4];
  const float* b_ih = (const float*)d_in[5];
  const float* b_hh = (const float*)d_in[6];
  const float* p1W1 = (const float*)d_in[7];
  const float* p1b1 = (const float*)d_in[8];
  const float* p1W2 = (const float*)d_in[9];
  const float* p1b2 = (const float*)d_in[10];
  const float* p2W1 = (const float*)d_in[11];
  const float* p2b1 = (const float*)d_in[12];
  const float* p2W2 = (const float*)d_in[13];
  const float* p2b2 = (const float*)d_in[14];
  const float* offW1 = (const float*)d_in[15];
  const float* offb1 = (const float*)d_in[16];
  const float* offW2 = (const float*)d_in[17];
  const float* offb2 = (const float*)d_in[18];
  const int* lens = (const int*)d_in[19];
  const int N = in_sizes[20];
  char* ws = (char*)d_ws;

  prep_w<<<1476, 256, 0, stream>>>(W_hh, W_ih, p1W2, p1W1, p2W1, offW1, p2W2, offW2, ws);
  prep_misc<<<34, 256, 0, stream>>>(b_ih, b_hh, W_ih, p1b2, p1b1, p2b1, offb1, p2b2,
                                    offb2, lens, ws);
  (void)hipFuncSetAttribute((const void*)rnn_main,
                            hipFuncAttributeMaxDynamicSharedMemorySize, SM_SZ);
  rnn_main<<<256, 512, SM_SZ, stream>>>(features, W_f2h, b_f2h, lens, ws,
                                        (float*)d_out, N);
}

// Round 11
// 8355.087 us; speedup vs baseline: 1.0255x; 1.0255x over previous
//
#include <hip/hip_runtime.h>
#include <hip/hip_bf16.h>
#include <cstddef>

// ---------------------------------------------------------------------------
// Round 11: consolidation. r9 skeleton (proven green) with:
//  (1) __launch_bounds__(512,1): 256-VGPR budget -> wgr[32] truly resident
//      (r9's cap of 128 spilled it to scratch = HBM: 360MB excess writes).
//  (2) single proven coherence path: relaxed agent atomics / sc0 sc1 batched
//      loads for ALL cross-block exchange (what r9 actually executed).
//  Flag-based sync (no central RMW in loop), watchdog-bounded polls.
// ---------------------------------------------------------------------------

typedef __attribute__((ext_vector_type(8))) __bf16 bf16x8;
typedef __attribute__((ext_vector_type(8))) short s16x8;
typedef __attribute__((ext_vector_type(4))) float f32x4;
typedef unsigned long long u64;
typedef unsigned int u32;

static constexpr int C_BLK = 16;

// ---- ws layout (bytes) ----
static constexpr size_t WS_WG = 0;
static constexpr size_t WS_WH = 4194304;
static constexpr size_t WS_WO = 5767168;
static constexpr size_t WS_BNF = 6045696;
static constexpr size_t WS_BCM = 6053888;
static constexpr size_t WS_BH = 6062080;
static constexpr size_t WS_BO = 6068224;
static constexpr size_t WS_BAR = 6070272;   // 16 * 128B central counters (init only)
static constexpr size_t WS_OFFS = 6072320;  // int[512]
static constexpr size_t WS_FLG = 6074368;   // 16 groups * 1024B: hfl[64] tfl[96]
static constexpr size_t WS_GRP = 6596608;   // 16 * GRPB
static constexpr size_t GRPB = 98304;
// group-internal offsets in SHORTS
static constexpr int TH1_O = 16384;
static constexpr int TH2_O = 32768;
static constexpr int OFFT_O = 40960;

// ---- dynamic LDS (bytes) ----
static constexpr int SM_HB = 0;
static constexpr int SM_T1 = 16384;
static constexpr int SM_TS = 32768;
static constexpr int SM_WH = 49152;
static constexpr int SM_GA = 147456;  // f32 gacc (ga*32+ul)*17+m
static constexpr int SM_OF = 156160;  // offs int[512]
static constexpr int SM_LN = 158208;  // lens int[16]
static constexpr int SM_SZ = 158272;

static constexpr int WDOG = 1 << 16;  // poll watchdog iterations

__device__ __forceinline__ unsigned short f2bf(float v) {
  __hip_bfloat16 h = __float2bfloat16(v);
  return *reinterpret_cast<unsigned short*>(&h);
}
__device__ __forceinline__ f32x4 mfma16(s16x8 a, s16x8 b, f32x4 c) {
  return __builtin_amdgcn_mfma_f32_16x16x32_bf16(
      __builtin_bit_cast(bf16x8, a), __builtin_bit_cast(bf16x8, b), c, 0, 0, 0);
}
__device__ __forceinline__ s16x8 ld8(const short* p) { return *(const s16x8*)p; }
__device__ __forceinline__ float sigm(float x) { return 1.0f / (1.0f + expf(-x)); }
__device__ __forceinline__ s16x8 ldA(const char* base, int row, int kb) {
  return *(const s16x8*)(base + row * 1024 + (kb ^ ((row & 7) << 4)));
}
#define DRAIN_VM asm volatile("s_waitcnt vmcnt(0)" ::: "memory")

// ---- proven exchange primitives: MALL-coherent (sc0 sc1 / agent atomics) ----
__device__ __forceinline__ u32 flag_ld(const u32* p) {
  return __hip_atomic_load(p, __ATOMIC_RELAXED, __HIP_MEMORY_SCOPE_AGENT);
}
__device__ __forceinline__ void u32_st(u32* p, u32 v) {
  __hip_atomic_store(p, v, __ATOMIC_RELAXED, __HIP_MEMORY_SCOPE_AGENT);
}
__device__ __forceinline__ void ld4x8(const u64* p0, const u64* p1, const u64* p2,
                                      const u64* p3, u64& a, u64& b, u64& c, u64& d) {
  asm volatile(
      "global_load_dwordx2 %0, %4, off sc0 sc1\n\t"
      "global_load_dwordx2 %1, %5, off sc0 sc1\n\t"
      "global_load_dwordx2 %2, %6, off sc0 sc1\n\t"
      "global_load_dwordx2 %3, %7, off sc0 sc1\n\t"
      "s_waitcnt vmcnt(0)"
      : "=&v"(a), "=&v"(b), "=&v"(c), "=&v"(d)
      : "v"(p0), "v"(p1), "v"(p2), "v"(p3) : "memory");
}

// ---------------- prep: bf16 fragment-order weights (validated) ---------------
__global__ void prep_w(const float* __restrict__ Whh, const float* __restrict__ Wih,
                       const float* __restrict__ p1W2, const float* __restrict__ p1W1,
                       const float* __restrict__ p2W1, const float* __restrict__ offW1,
                       const float* __restrict__ p2W2, const float* __restrict__ offW2,
                       char* __restrict__ ws) {
  int s = blockIdx.x * 256 + threadIdx.x;
  if (s < 262144) {
    int tile = s >> 11, rem = s & 2047;
    int kc = rem >> 6, lane = rem & 63;
    int n = tile * 16 + (lane & 15);
    int k0 = kc * 32 + ((lane >> 4) << 3);
    s16x8 o;
    if (kc < 16) {
      const float* src = Whh + (size_t)n * 512 + k0;
      for (int i = 0; i < 8; i++) o[i] = (short)f2bf(src[i]);
    } else {
      int c0 = k0 - 512;
      float acc[8] = {0, 0, 0, 0, 0, 0, 0, 0};
      const float* wr = Wih + (size_t)n * 128;
      for (int j = 0; j < 128; j++) {
        float wij = wr[j];
        const float* pr = p1W2 + (size_t)j * 512 + c0;
        for (int i = 0; i < 8; i++) acc[i] += wij * pr[i];
      }
      for (int i = 0; i < 8; i++) o[i] = (short)f2bf(acc[i]);
    }
    *(s16x8*)((short*)(ws + WS_WG) + (size_t)(tile * 32 + kc) * 512 + lane * 8) = o;
  } else if (s < 262144 + 98304) {
    int z = s - 262144;
    int tile = z >> 10, rem = z & 1023;
    int kc = rem >> 6, lane = rem & 63;
    int n = tile * 16 + (lane & 15);
    int k0 = kc * 32 + ((lane >> 4) << 3);
    const float* src = (n < 512) ? p1W1 + (size_t)n * 512
                     : (n < 1024) ? p2W1 + (size_t)(n - 512) * 512
                                  : offW1 + (size_t)(n - 1024) * 512;
    s16x8 o;
    for (int i = 0; i < 8; i++) o[i] = (short)f2bf(src[k0 + i]);
    *(s16x8*)((short*)(ws + WS_WH) + (size_t)(tile * 16 + kc) * 512 + lane * 8) = o;
  } else if (s < 262144 + 98304 + 17408) {
    int z = s - 262144 - 98304;
    int tile = z >> 10, rem = z & 1023;
    int kc = rem >> 6, lane = rem & 63;
    int n = tile * 16 + (lane & 15);
    int k0 = kc * 32 + ((lane >> 4) << 3);
    s16x8 o;
    for (int i = 0; i < 8; i++) {
      int k = k0 + i;
      float v = (n < 128) ? p1W2[(size_t)n * 512 + k]
              : (n < 256) ? p2W2[(size_t)(n - 128) * 512 + k]
              : (n == 256) ? offW2[k] : 0.f;
      o[i] = (short)f2bf(v);
    }
    *(s16x8*)((short*)(ws + WS_WO) + (size_t)(tile * 16 + kc) * 512 + lane * 8) = o;
  }
}

// ---------------- prep: biases, counters, offs, flags -------------------------
__global__ void prep_misc(const float* __restrict__ b_ih, const float* __restrict__ b_hh,
                          const float* __restrict__ Wih, const float* __restrict__ p1b2,
                          const float* __restrict__ p1b1, const float* __restrict__ p2b1,
                          const float* __restrict__ offb1, const float* __restrict__ p2b2,
                          const float* __restrict__ offb2, const int* __restrict__ lens,
                          char* __restrict__ ws) {
  int i = blockIdx.x * 256 + threadIdx.x;
  if (i < 2048) {
    float bn = b_ih[i] + b_hh[i];
    ((float*)(ws + WS_BNF))[i] = bn;
    float acc = 0.f;
    const float* wr = Wih + (size_t)i * 128;
    for (int j = 0; j < 128; j++) acc += wr[j] * p1b2[j];
    ((float*)(ws + WS_BCM))[i] = bn + acc;
  } else if (i < 3584) {
    int j = i - 2048;
    ((float*)(ws + WS_BH))[j] =
        j < 512 ? p1b1[j] : (j < 1024 ? p2b1[j - 512] : offb1[j - 1024]);
  } else if (i < 3856) {
    int j = i - 3584;
    ((float*)(ws + WS_BO))[j] =
        j < 128 ? p1b2[j] : (j < 256 ? p2b2[j - 128] : (j == 256 ? offb2[0] : 0.f));
  } else if (i < 3872) {
    *(int*)(ws + WS_BAR + (size_t)(i - 3856) * 128) = 0;
  } else if (i < 4384) {
    int t = i - 3872;
    int s = 0;
    for (int b = 0; b < 256; b++) { int L = lens[b]; s += (L < t ? L : t); }
    ((int*)(ws + WS_OFFS))[t] = s;
  } else if (i < 4384 + 4096) {
    ((u32*)(ws + WS_FLG))[i - 4384] = 0;
  }
}

// ---------------- main persistent kernel -------------------------------------
__launch_bounds__(512, 1)
__global__ void rnn_main(const float* __restrict__ features, const float* __restrict__ Wf2h,
                         const float* __restrict__ bf2h, const int* __restrict__ lens,
                         char* __restrict__ ws, float* __restrict__ out, int N) {
  extern __shared__ char sm[];
  const int g = blockIdx.x & 15;
  const int rank = blockIdx.x >> 4;
  const int tid = threadIdx.x, w = tid >> 6, l = tid & 63, lr = l & 15, hi = l >> 4;

  const short* Wg = (const short*)(ws + WS_WG);
  const short* Wh = (const short*)(ws + WS_WH);
  const short* Wo = (const short*)(ws + WS_WO);
  const float* bnf = (const float*)(ws + WS_BNF);
  const float* bcm = (const float*)(ws + WS_BCM);
  const float* bh = (const float*)(ws + WS_BH);
  const float* bo = (const float*)(ws + WS_BO);
  const int* offs_g = (const int*)(ws + WS_OFFS);
  int* cnt = (int*)(ws + WS_BAR + (size_t)g * 128);
  u32* hfl = (u32*)(ws + WS_FLG + (size_t)g * 1024);
  u32* tfl = hfl + 64;
  short* hb_ = (short*)(ws + WS_GRP + (size_t)g * GRPB);
  short* t1b = hb_ + TH1_O;
  short* t2b = hb_ + TH2_O;
  short* tob = hb_ + OFFT_O;

  int* lens_s = (int*)(sm + SM_LN);
  int* offs_s = (int*)(sm + SM_OF);
  float* gacc = (float*)(sm + SM_GA);  // idx (ga*32+ul)*17 + m

  if (tid < 16) lens_s[tid] = lens[g * 16 + tid];
  offs_s[tid] = offs_g[tid];

  // stage Wh slice into LDS (once)
  for (int i = tid; i < 6144; i += 512) {
    int lt = i >> 10, c = i & 1023;
    int sec = lt >> 1, j = lt & 1;
    int T = sec * 32 + rank * 2 + j;
    *(s16x8*)(sm + SM_WH + (size_t)i * 16) = ld8(Wh + (size_t)T * 8192 + (size_t)c * 8);
  }

  // ---- init: h0/c0 (tid<256, 2 adjacent units each), publish agent-scope ----
  const int m_c = tid >> 4, p_c = tid & 15;
  const int u0 = rank * 32 + 2 * p_c;
  float creg0 = 0.f, creg1 = 0.f;
  float bn0[4], bn1[4], bc0[4], bc1[4];
  if (tid < 256) {
    const float* fr = features + (size_t)(g * 16 + m_c) * 256;
    const float* wa = Wf2h + (size_t)(2 * u0) * 256;
    float ah0 = 0.f, ac0 = 0.f, ah1 = 0.f, ac1 = 0.f;
    for (int k = 0; k < 256; k++) {
      float fv = fr[k];
      ah0 += fv * wa[k];
      ac0 += fv * wa[256 + k];
      ah1 += fv * wa[512 + k];
      ac1 += fv * wa[768 + k];
    }
    ah0 += bf2h[2 * u0];     ac0 += bf2h[2 * u0 + 1];
    ah1 += bf2h[2 * u0 + 2]; ac1 += bf2h[2 * u0 + 3];
    creg0 = ac0; creg1 = ac1;
    u32 pk = (u32)f2bf(ah0) | ((u32)f2bf(ah1) << 16);
    u32_st((u32*)hb_ + m_c * 256 + rank * 16 + p_c, pk);  // buffer 0
    for (int ga = 0; ga < 4; ga++) {
      bn0[ga] = bnf[ga * 512 + u0];     bn1[ga] = bnf[ga * 512 + u0 + 1];
      bc0[ga] = bcm[ga * 512 + u0];     bc1[ga] = bcm[ga * 512 + u0 + 1];
    }
  }

  // per-wave persistent gates weights: 32 x s16x8 = 128 VGPRs (now resident)
  const int ga_w = w & 3, j0_w = w >> 2;
  const int tileG = ga_w * 32 + rank * 2 + j0_w;
  s16x8 wgr[32];
  {
    const short* wb = Wg + (size_t)tileG * 16384 + l * 8;
#pragma unroll
    for (int kc = 0; kc < 32; ++kc) wgr[kc] = ld8(wb + (size_t)kc * 512);
  }
  const int secw = w >> 1;
  const int T2 = secw * 32 + rank * 2 + (w & 1);
  const int lt2 = secw * 2 + (w & 1);
  float bh_r = (w < 6) ? bh[T2 * 16 + lr] : 0.f;
  float bo_r = (w == 4) ? bo[rank * 16 + lr] : ((w == 5 && rank == 7) ? bo[256] : 0.f);

  DRAIN_VM;
  __syncthreads();
  int steps = 0;
  for (int i = 0; i < 16; i++) steps = max(steps, lens_s[i]);

  // central agent-scope barrier (watchdog-bounded): h0 published group-wide
  if (tid == 0) {
    __hip_atomic_fetch_add(cnt, 1, __ATOMIC_RELAXED, __HIP_MEMORY_SCOPE_AGENT);
    int wd = 0;
    while (__hip_atomic_load(cnt, __ATOMIC_RELAXED, __HIP_MEMORY_SCOPE_AGENT) < C_BLK &&
           ++wd < (1 << 20))
      __builtin_amdgcn_s_sleep(1);
  }
  __syncthreads();

  const size_t base1 = (size_t)N * 128;
  const size_t base2 = 2 * base1;
  const size_t base3 = base2 + (size_t)N;

  // staging geometry
  const int j0c = tid, j1c = tid + 512;
  const int r0 = j0c >> 6, k0b = (j0c & 63) << 4;
  const int r1 = j1c >> 6, k1b = (j1c & 63) << 4;
  char* d0h = sm + SM_HB + r0 * 1024 + (k0b ^ ((r0 & 7) << 4));
  char* d1h = sm + SM_HB + r1 * 1024 + (k1b ^ ((r1 & 7) << 4));
  char* d0t = sm + SM_T1 + r0 * 1024 + (k0b ^ ((r0 & 7) << 4));
  char* d1t = sm + SM_T1 + r1 * 1024 + (k1b ^ ((r1 & 7) << 4));
  char* d0s = sm + SM_TS + r0 * 1024 + (k0b ^ ((r0 & 7) << 4));
  char* d1s = sm + SM_TS + r1 * 1024 + (k1b ^ ((r1 & 7) << 4));

  // doP3(tt): p1/p2 (wave 4) + offsets (wave 5, rank 7); reads SM_T1/SM_TS
  auto doP3 = [&](int tt) {
    if (tt < 0) return;
    const int offs_t = offs_s[tt];
    if (w == 4) {
      s16x8 wo[16];
      const short* wb = Wo + (size_t)(rank * 16) * 512 + l * 8;
#pragma unroll
      for (int kc = 0; kc < 16; ++kc) wo[kc] = ld8(wb + (size_t)kc * 512);
      f32x4 acc = {0.f, 0.f, 0.f, 0.f};
      const char* ab = sm + (rank < 8 ? SM_T1 : SM_TS);
#pragma unroll
      for (int kc = 0; kc < 16; ++kc)
        acc = mfma16(ldA(ab, lr, kc * 64 + hi * 16), wo[kc], acc);
      const int nW = rank * 16 + lr;
      for (int r = 0; r < 4; r++) {
        int m = hi * 4 + r;
        if (tt < lens_s[m]) {
          size_t pos = (size_t)(offs_t + g * 16 + m);
          float v = acc[r] + bo_r;
          if (rank < 8) {
            out[pos * 128 + nW] = v;
            out[base3 + pos * 128 + nW] = v;
          } else {
            out[base1 + pos * 128 + (nW - 128)] = v;
          }
        }
      }
    } else if (w == 5 && rank == 7) {
      s16x8 wo[16];
      const short* wb = Wo + (size_t)(16 * 16) * 512 + l * 8;
#pragma unroll
      for (int kc = 0; kc < 16; ++kc) wo[kc] = ld8(wb + (size_t)kc * 512);
      f32x4 acc = {0.f, 0.f, 0.f, 0.f};
#pragma unroll
      for (int kc = 0; kc < 16; ++kc)
        acc = mfma16(ldA(sm + SM_TS, lr, kc * 64 + hi * 16), wo[kc], acc);
      if (lr == 0) {
        for (int r = 0; r < 4; r++) {
          int m = hi * 4 + r;
          if (tt < lens_s[m])
            out[base2 + (size_t)(offs_t + g * 16 + m)] = acc[r] + bo_r;
        }
      }
    }
  };

  // prologue: stage SM_HB = h0 (batched sc0sc1), SM_T1 = 0
  {
    const u64* hq = (const u64*)hb_;
    u64 a, b, c, d;
    ld4x8(hq + 2 * j0c, hq + 2 * j0c + 1, hq + 2 * j1c, hq + 2 * j1c + 1, a, b, c, d);
    *(u64*)d0h = a; *(u64*)(d0h + 8) = b;
    *(u64*)d1h = c; *(u64*)(d1h + 8) = d;
    *(u64*)d0t = 0ull; *(u64*)(d0t + 8) = 0ull;
    *(u64*)d1t = 0ull; *(u64*)(d1t + 8) = 0ull;
  }
  __syncthreads();
  f32x4 accP1 = {0.f, 0.f, 0.f, 0.f};
#pragma unroll
  for (int kc = 0; kc < 16; ++kc)
    accP1 = mfma16(ldA(sm + SM_HB, lr, kc * 64 + hi * 16), wgr[kc], accP1);

  for (int t = 0; t < steps; ++t) {
    const int bufp = (t & 1) ^ 1;  // write parity

    // ---- A: P1 finish (th1(t-1) half) ----
    {
      f32x4 acc = accP1;
#pragma unroll
      for (int kc = 0; kc < 16; ++kc)
        acc = mfma16(ldA(sm + SM_T1, lr, kc * 64 + hi * 16), wgr[16 + kc], acc);
      for (int r = 0; r < 4; r++)
        gacc[(ga_w * 32 + j0_w * 16 + lr) * 17 + hi * 4 + r] = acc[r];
    }
    __syncthreads();  // S1

    // ---- B: cell+publish (w<4) | doP3(t-1) (w4,5) | poll h-flags (w7) ----
    if (w < 4) {
      const int ua = 2 * p_c;
      float gi0 = gacc[(0 * 32 + ua) * 17 + m_c] + (t ? bc0[0] : bn0[0]);
      float gf0 = gacc[(1 * 32 + ua) * 17 + m_c] + (t ? bc0[1] : bn0[1]);
      float gg0 = gacc[(2 * 32 + ua) * 17 + m_c] + (t ? bc0[2] : bn0[2]);
      float go0 = gacc[(3 * 32 + ua) * 17 + m_c] + (t ? bc0[3] : bn0[3]);
      float gi1 = gacc[(0 * 32 + ua + 1) * 17 + m_c] + (t ? bc1[0] : bn1[0]);
      float gf1 = gacc[(1 * 32 + ua + 1) * 17 + m_c] + (t ? bc1[1] : bn1[1]);
      float gg1 = gacc[(2 * 32 + ua + 1) * 17 + m_c] + (t ? bc1[2] : bn1[2]);
      float go1 = gacc[(3 * 32 + ua + 1) * 17 + m_c] + (t ? bc1[3] : bn1[3]);
      float c0 = sigm(gf0) * creg0 + sigm(gi0) * tanhf(gg0);
      float c1 = sigm(gf1) * creg1 + sigm(gi1) * tanhf(gg1);
      creg0 = c0; creg1 = c1;
      float h0v = sigm(go0) * tanhf(c0);
      float h1v = sigm(go1) * tanhf(c1);
      u32 pk = (u32)f2bf(h0v) | ((u32)f2bf(h1v) << 16);
      u32_st((u32*)hb_ + bufp * 4096 + m_c * 256 + rank * 16 + p_c, pk);
      DRAIN_VM;
      if (l == 0) u32_st(hfl + rank * 4 + w, (u32)(t + 1));
    } else if (w == 4 || w == 5) {
      doP3(t - 1);
    } else if (w == 7) {
      const u32* fp = hfl + l;
      u32 v;
      int wd = 0;
      do { v = flag_ld(fp); } while ((int)v < t + 1 && ++wd < WDOG);
    }
    __syncthreads();  // S2

    // ---- C: stage h(t) -> SM_HB ----
    {
      const u64* hq = (const u64*)hb_ + (size_t)bufp * 2048;
      u64 a, b, c, d;
      ld4x8(hq + 2 * j0c, hq + 2 * j0c + 1, hq + 2 * j1c, hq + 2 * j1c + 1, a, b, c, d);
      *(u64*)d0h = a; *(u64*)(d0h + 8) = b;
      *(u64*)d1h = c; *(u64*)(d1h + 8) = d;
    }
    __syncthreads();  // S3

    // ---- D: P2+publish (w<6) | accP1 + poll th-flags (w6,7) ----
    if (w < 6) {
      f32x4 acc = {0.f, 0.f, 0.f, 0.f};
      const char* wl = sm + SM_WH + lt2 * 16384 + l * 16;
#pragma unroll
      for (int kc = 0; kc < 16; ++kc)
        acc = mfma16(ldA(sm + SM_HB, lr, kc * 64 + hi * 16),
                     *(const s16x8*)(wl + kc * 1024), acc);
      u32 my[4];
      for (int r = 0; r < 4; r++) my[r] = (u32)f2bf(tanhf(acc[r] + bh_r));
      u32 wordv[4];
      for (int r = 0; r < 4; r++) {
        u32 oth = (u32)__shfl_xor((int)my[r], 1, 64);
        wordv[r] = my[r] | (oth << 16);
      }
      if (!(l & 1)) {
        const int cp = lr >> 1;
        for (int r = 0; r < 4; r++) {
          int m = hi * 4 + r;
          u32* dst = (T2 < 32) ? (u32*)t1b + bufp * 4096 + m * 256 + T2 * 8 + cp
                   : (T2 < 64) ? (u32*)t2b + m * 256 + (T2 - 32) * 8 + cp
                               : (u32*)tob + m * 256 + (T2 - 64) * 8 + cp;
          u32_st(dst, wordv[r]);
        }
      }
      DRAIN_VM;
      if (l == 0) u32_st(tfl + rank * 6 + w, (u32)(t + 1));
      f32x4 ap = {0.f, 0.f, 0.f, 0.f};
#pragma unroll
      for (int kc = 0; kc < 16; ++kc)
        ap = mfma16(ldA(sm + SM_HB, lr, kc * 64 + hi * 16), wgr[kc], ap);
      accP1 = ap;
    } else {
      f32x4 ap = {0.f, 0.f, 0.f, 0.f};
#pragma unroll
      for (int kc = 0; kc < 16; ++kc)
        ap = mfma16(ldA(sm + SM_HB, lr, kc * 64 + hi * 16), wgr[kc], ap);
      accP1 = ap;
      if (l < 48) {
        const u32* fp = tfl + ((w == 6) ? l : 48 + l);
        u32 v;
        int wd = 0;
        do { v = flag_ld(fp); } while ((int)v < t + 1 && ++wd < WDOG);
      }
    }
    __syncthreads();  // S4

    // ---- E: stage th1(t) -> SM_T1 (+ th2/tob -> SM_TS for ranks>=7) ----
    {
      const u64* tq = (const u64*)t1b + (size_t)bufp * 2048;
      u64 a, b, c, d;
      ld4x8(tq + 2 * j0c, tq + 2 * j0c + 1, tq + 2 * j1c, tq + 2 * j1c + 1, a, b, c, d);
      *(u64*)d0t = a; *(u64*)(d0t + 8) = b;
      *(u64*)d1t = c; *(u64*)(d1t + 8) = d;
      if (rank >= 7) {
        const u64* sq = (const u64*)(rank == 7 ? tob : t2b);
        u64 e, f2, gq, h2;
        ld4x8(sq + 2 * j0c, sq + 2 * j0c + 1, sq + 2 * j1c, sq + 2 * j1c + 1,
              e, f2, gq, h2);
        *(u64*)d0s = e; *(u64*)(d0s + 8) = f2;
        *(u64*)d1s = gq; *(u64*)(d1s + 8) = h2;
      }
    }
    __syncthreads();  // S5
  }
  doP3(steps - 1);
}

extern "C" void kernel_launch(void* const* d_in, const int* in_sizes, int n_in,
                              void* d_out, int out_size, void* d_ws, size_t ws_size,
                              hipStream_t stream) {
  const float* features = (const float*)d_in[0];
  const float* W_f2h = (const float*)d_in[1];
  const float* b_f2h = (const float*)d_in[2];
  const float* W_ih = (const float*)d_in[3];
  const float* W_hh = (const float*)d_in[4];
  const float* b_ih = (const float*)d_in[5];
  const float* b_hh = (const float*)d_in[6];
  const float* p1W1 = (const float*)d_in[7];
  const float* p1b1 = (const float*)d_in[8];
  const float* p1W2 = (const float*)d_in[9];
  const float* p1b2 = (const float*)d_in[10];
  const float* p2W1 = (const float*)d_in[11];
  const float* p2b1 = (const float*)d_in[12];
  const float* p2W2 = (const float*)d_in[13];
  const float* p2b2 = (const float*)d_in[14];
  const float* offW1 = (const float*)d_in[15];
  const float* offb1 = (const float*)d_in[16];
  const float* offW2 = (const float*)d_in[17];
  const float* offb2 = (const float*)d_in[18];
  const int* lens = (const int*)d_in[19];
  const int N = in_sizes[20];
  char* ws = (char*)d_ws;

  prep_w<<<1476, 256, 0, stream>>>(W_hh, W_ih, p1W2, p1W1, p2W1, offW1, p2W2, offW2, ws);
  prep_misc<<<34, 256, 0, stream>>>(b_ih, b_hh, W_ih, p1b2, p1b1, p2b1, offb1, p2b2,
                                    offb2, lens, ws);
  (void)hipFuncSetAttribute((const void*)rnn_main,
                            hipFuncAttributeMaxDynamicSharedMemorySize, SM_SZ);
  rnn_main<<<256, 512, SM_SZ, stream>>>(features, W_f2h, b_f2h, lens, ws,
                                        (float*)d_out, N);
}

// Round 12
// 6059.440 us; speedup vs baseline: 1.4141x; 1.3789x over previous
//
#include <hip/hip_runtime.h>
#include <hip/hip_bf16.h>
#include <cstddef>

// ---------------------------------------------------------------------------
// Round 12: r7's proven overlap structure + per-rank flag barrier (no central
// RMW), single-wave sleep-backed polls, issue/wait-split batched stage loads
// (doP3 hides h-stage; accP1 hides th1-stage). Exchange mechanics: relaxed
// agent atomics / sc0 sc1 loads (the only HW-proven coherent path).
// ---------------------------------------------------------------------------

typedef __attribute__((ext_vector_type(8))) __bf16 bf16x8;
typedef __attribute__((ext_vector_type(8))) short s16x8;
typedef __attribute__((ext_vector_type(4))) float f32x4;
typedef unsigned long long u64;
typedef unsigned int u32;

static constexpr int C_BLK = 16;

// ---- ws layout (bytes) ----
static constexpr size_t WS_WG = 0;
static constexpr size_t WS_WH = 4194304;
static constexpr size_t WS_WO = 5767168;
static constexpr size_t WS_BNF = 6045696;
static constexpr size_t WS_BCM = 6053888;
static constexpr size_t WS_BH = 6062080;
static constexpr size_t WS_BO = 6068224;
static constexpr size_t WS_BAR = 6070272;   // 16 * 128B central counters (init only)
static constexpr size_t WS_OFFS = 6072320;  // int[512]
static constexpr size_t WS_FLG = 6074368;   // 16 groups * 1024B: hfl[16] @0, tfl[16] @64
static constexpr size_t WS_GRP = 6596608;   // 16 * GRPB
static constexpr size_t GRPB = 98304;
// group-internal offsets in SHORTS
static constexpr int TH1_O = 16384;
static constexpr int TH2_O = 32768;
static constexpr int OFFT_O = 40960;

// ---- dynamic LDS (bytes) ----
static constexpr int SM_HB = 0;
static constexpr int SM_T1 = 16384;
static constexpr int SM_TS = 32768;
static constexpr int SM_WH = 49152;
static constexpr int SM_GA = 147456;  // f32 gacc (ga*32+ul)*17+m
static constexpr int SM_OF = 156160;  // offs int[512]
static constexpr int SM_LN = 158208;  // lens int[16]
static constexpr int SM_SZ = 158272;

static constexpr int WDOG = 1 << 20;  // poll watchdog iterations (with sleep)

__device__ __forceinline__ unsigned short f2bf(float v) {
  __hip_bfloat16 h = __float2bfloat16(v);
  return *reinterpret_cast<unsigned short*>(&h);
}
__device__ __forceinline__ f32x4 mfma16(s16x8 a, s16x8 b, f32x4 c) {
  return __builtin_amdgcn_mfma_f32_16x16x32_bf16(
      __builtin_bit_cast(bf16x8, a), __builtin_bit_cast(bf16x8, b), c, 0, 0, 0);
}
__device__ __forceinline__ s16x8 ld8(const short* p) { return *(const s16x8*)p; }
__device__ __forceinline__ float sigm(float x) { return 1.0f / (1.0f + expf(-x)); }
__device__ __forceinline__ s16x8 ldA(const char* base, int row, int kb) {
  return *(const s16x8*)(base + row * 1024 + (kb ^ ((row & 7) << 4)));
}
#define DRAIN_VM asm volatile("s_waitcnt vmcnt(0)" ::: "memory")

// ---- proven exchange primitives (MALL-coherent) ----
__device__ __forceinline__ u32 flag_ld(const u32* p) {
  return __hip_atomic_load(p, __ATOMIC_RELAXED, __HIP_MEMORY_SCOPE_AGENT);
}
__device__ __forceinline__ void u32_st(u32* p, u32 v) {
  __hip_atomic_store(p, v, __ATOMIC_RELAXED, __HIP_MEMORY_SCOPE_AGENT);
}
// issue 4 coherent 8B loads WITHOUT waiting (values invalid until wait_vm4)
__device__ __forceinline__ void ld4x8_issue(const u64* p0, const u64* p1,
                                            const u64* p2, const u64* p3,
                                            u64& a, u64& b, u64& c, u64& d) {
  asm volatile(
      "global_load_dwordx2 %0, %4, off sc0 sc1\n\t"
      "global_load_dwordx2 %1, %5, off sc0 sc1\n\t"
      "global_load_dwordx2 %2, %6, off sc0 sc1\n\t"
      "global_load_dwordx2 %3, %7, off sc0 sc1"
      : "=&v"(a), "=&v"(b), "=&v"(c), "=&v"(d)
      : "v"(p0), "v"(p1), "v"(p2), "v"(p3) : "memory");
}
// wait for outstanding loads; data-dependency pins consumers after this
__device__ __forceinline__ void wait_vm4(u64& a, u64& b, u64& c, u64& d) {
  asm volatile("s_waitcnt vmcnt(0)"
               : "+v"(a), "+v"(b), "+v"(c), "+v"(d)::"memory");
}

// ---------------- prep: bf16 fragment-order weights (validated) ---------------
__global__ void prep_w(const float* __restrict__ Whh, const float* __restrict__ Wih,
                       const float* __restrict__ p1W2, const float* __restrict__ p1W1,
                       const float* __restrict__ p2W1, const float* __restrict__ offW1,
                       const float* __restrict__ p2W2, const float* __restrict__ offW2,
                       char* __restrict__ ws) {
  int s = blockIdx.x * 256 + threadIdx.x;
  if (s < 262144) {
    int tile = s >> 11, rem = s & 2047;
    int kc = rem >> 6, lane = rem & 63;
    int n = tile * 16 + (lane & 15);
    int k0 = kc * 32 + ((lane >> 4) << 3);
    s16x8 o;
    if (kc < 16) {
      const float* src = Whh + (size_t)n * 512 + k0;
      for (int i = 0; i < 8; i++) o[i] = (short)f2bf(src[i]);
    } else {
      int c0 = k0 - 512;
      float acc[8] = {0, 0, 0, 0, 0, 0, 0, 0};
      const float* wr = Wih + (size_t)n * 128;
      for (int j = 0; j < 128; j++) {
        float wij = wr[j];
        const float* pr = p1W2 + (size_t)j * 512 + c0;
        for (int i = 0; i < 8; i++) acc[i] += wij * pr[i];
      }
      for (int i = 0; i < 8; i++) o[i] = (short)f2bf(acc[i]);
    }
    *(s16x8*)((short*)(ws + WS_WG) + (size_t)(tile * 32 + kc) * 512 + lane * 8) = o;
  } else if (s < 262144 + 98304) {
    int z = s - 262144;
    int tile = z >> 10, rem = z & 1023;
    int kc = rem >> 6, lane = rem & 63;
    int n = tile * 16 + (lane & 15);
    int k0 = kc * 32 + ((lane >> 4) << 3);
    const float* src = (n < 512) ? p1W1 + (size_t)n * 512
                     : (n < 1024) ? p2W1 + (size_t)(n - 512) * 512
                                  : offW1 + (size_t)(n - 1024) * 512;
    s16x8 o;
    for (int i = 0; i < 8; i++) o[i] = (short)f2bf(src[k0 + i]);
    *(s16x8*)((short*)(ws + WS_WH) + (size_t)(tile * 16 + kc) * 512 + lane * 8) = o;
  } else if (s < 262144 + 98304 + 17408) {
    int z = s - 262144 - 98304;
    int tile = z >> 10, rem = z & 1023;
    int kc = rem >> 6, lane = rem & 63;
    int n = tile * 16 + (lane & 15);
    int k0 = kc * 32 + ((lane >> 4) << 3);
    s16x8 o;
    for (int i = 0; i < 8; i++) {
      int k = k0 + i;
      float v = (n < 128) ? p1W2[(size_t)n * 512 + k]
              : (n < 256) ? p2W2[(size_t)(n - 128) * 512 + k]
              : (n == 256) ? offW2[k] : 0.f;
      o[i] = (short)f2bf(v);
    }
    *(s16x8*)((short*)(ws + WS_WO) + (size_t)(tile * 16 + kc) * 512 + lane * 8) = o;
  }
}

// ---------------- prep: biases, counters, offs, flags -------------------------
__global__ void prep_misc(const float* __restrict__ b_ih, const float* __restrict__ b_hh,
                          const float* __restrict__ Wih, const float* __restrict__ p1b2,
                          const float* __restrict__ p1b1, const float* __restrict__ p2b1,
                          const float* __restrict__ offb1, const float* __restrict__ p2b2,
                          const float* __restrict__ offb2, const int* __restrict__ lens,
                          char* __restrict__ ws) {
  int i = blockIdx.x * 256 + threadIdx.x;
  if (i < 2048) {
    float bn = b_ih[i] + b_hh[i];
    ((float*)(ws + WS_BNF))[i] = bn;
    float acc = 0.f;
    const float* wr = Wih + (size_t)i * 128;
    for (int j = 0; j < 128; j++) acc += wr[j] * p1b2[j];
    ((float*)(ws + WS_BCM))[i] = bn + acc;
  } else if (i < 3584) {
    int j = i - 2048;
    ((float*)(ws + WS_BH))[j] =
        j < 512 ? p1b1[j] : (j < 1024 ? p2b1[j - 512] : offb1[j - 1024]);
  } else if (i < 3856) {
    int j = i - 3584;
    ((float*)(ws + WS_BO))[j] =
        j < 128 ? p1b2[j] : (j < 256 ? p2b2[j - 128] : (j == 256 ? offb2[0] : 0.f));
  } else if (i < 3872) {
    *(int*)(ws + WS_BAR + (size_t)(i - 3856) * 128) = 0;
  } else if (i < 4384) {
    int t = i - 3872;
    int s = 0;
    for (int b = 0; b < 256; b++) { int L = lens[b]; s += (L < t ? L : t); }
    ((int*)(ws + WS_OFFS))[t] = s;
  } else if (i < 4384 + 4096) {
    ((u32*)(ws + WS_FLG))[i - 4384] = 0;
  }
}

// ---------------- main persistent kernel -------------------------------------
__launch_bounds__(512, 1)
__global__ void rnn_main(const float* __restrict__ features, const float* __restrict__ Wf2h,
                         const float* __restrict__ bf2h, const int* __restrict__ lens,
                         char* __restrict__ ws, float* __restrict__ out, int N) {
  extern __shared__ char sm[];
  const int g = blockIdx.x & 15;
  const int rank = blockIdx.x >> 4;
  const int tid = threadIdx.x, w = tid >> 6, l = tid & 63, lr = l & 15, hi = l >> 4;

  const short* Wg = (const short*)(ws + WS_WG);
  const short* Wh = (const short*)(ws + WS_WH);
  const short* Wo = (const short*)(ws + WS_WO);
  const float* bnf = (const float*)(ws + WS_BNF);
  const float* bcm = (const float*)(ws + WS_BCM);
  const float* bh = (const float*)(ws + WS_BH);
  const float* bo = (const float*)(ws + WS_BO);
  const int* offs_g = (const int*)(ws + WS_OFFS);
  int* cnt = (int*)(ws + WS_BAR + (size_t)g * 128);
  u32* hfl = (u32*)(ws + WS_FLG + (size_t)g * 1024);
  u32* tfl = hfl + 16;
  short* hb_ = (short*)(ws + WS_GRP + (size_t)g * GRPB);
  short* t1b = hb_ + TH1_O;
  short* t2b = hb_ + TH2_O;
  short* tob = hb_ + OFFT_O;

  int* lens_s = (int*)(sm + SM_LN);
  int* offs_s = (int*)(sm + SM_OF);
  float* gacc = (float*)(sm + SM_GA);  // idx (ga*32+ul)*17 + m

  if (tid < 16) lens_s[tid] = lens[g * 16 + tid];
  offs_s[tid] = offs_g[tid];

  // stage Wh slice into LDS (once)
  for (int i = tid; i < 6144; i += 512) {
    int lt = i >> 10, c = i & 1023;
    int sec = lt >> 1, j = lt & 1;
    int T = sec * 32 + rank * 2 + j;
    *(s16x8*)(sm + SM_WH + (size_t)i * 16) = ld8(Wh + (size_t)T * 8192 + (size_t)c * 8);
  }

  // ---- init: h0/c0 (tid<256, 2 adjacent units each) ----
  const int m_c = tid >> 4, p_c = tid & 15;
  const int u0 = rank * 32 + 2 * p_c;
  float creg0 = 0.f, creg1 = 0.f;
  float bn0[4], bn1[4], bc0[4], bc1[4];
  if (tid < 256) {
    const float* fr = features + (size_t)(g * 16 + m_c) * 256;
    const float* wa = Wf2h + (size_t)(2 * u0) * 256;
    float ah0 = 0.f, ac0 = 0.f, ah1 = 0.f, ac1 = 0.f;
    for (int k = 0; k < 256; k++) {
      float fv = fr[k];
      ah0 += fv * wa[k];
      ac0 += fv * wa[256 + k];
      ah1 += fv * wa[512 + k];
      ac1 += fv * wa[768 + k];
    }
    ah0 += bf2h[2 * u0];     ac0 += bf2h[2 * u0 + 1];
    ah1 += bf2h[2 * u0 + 2]; ac1 += bf2h[2 * u0 + 3];
    creg0 = ac0; creg1 = ac1;
    u32 pk = (u32)f2bf(ah0) | ((u32)f2bf(ah1) << 16);
    u32_st((u32*)hb_ + m_c * 256 + rank * 16 + p_c, pk);  // buffer 0
    for (int ga = 0; ga < 4; ga++) {
      bn0[ga] = bnf[ga * 512 + u0];     bn1[ga] = bnf[ga * 512 + u0 + 1];
      bc0[ga] = bcm[ga * 512 + u0];     bc1[ga] = bcm[ga * 512 + u0 + 1];
    }
  }

  // per-wave gates weights
  const int ga_w = w & 3, j0_w = w >> 2;
  const int tileG = ga_w * 32 + rank * 2 + j0_w;
  s16x8 wgr[32];
  {
    const short* wb = Wg + (size_t)tileG * 16384 + l * 8;
#pragma unroll
    for (int kc = 0; kc < 32; ++kc) wgr[kc] = ld8(wb + (size_t)kc * 512);
  }
  const int secw = w >> 1;
  const int T2 = secw * 32 + rank * 2 + (w & 1);
  const int lt2 = secw * 2 + (w & 1);
  float bh_r = (w < 6) ? bh[T2 * 16 + lr] : 0.f;
  float bo_r = (w == 0) ? bo[rank * 16 + lr] : ((w == 1 && rank == 7) ? bo[256] : 0.f);

  DRAIN_VM;
  __syncthreads();
  int steps = 0;
  for (int i = 0; i < 16; i++) steps = max(steps, lens_s[i]);

  // one-time central barrier: h0 published group-wide
  if (tid == 0) {
    __hip_atomic_fetch_add(cnt, 1, __ATOMIC_RELAXED, __HIP_MEMORY_SCOPE_AGENT);
    int wd = 0;
    while (__hip_atomic_load(cnt, __ATOMIC_RELAXED, __HIP_MEMORY_SCOPE_AGENT) < C_BLK &&
           ++wd < WDOG)
      __builtin_amdgcn_s_sleep(1);
  }
  __syncthreads();

  const size_t base1 = (size_t)N * 128;
  const size_t base2 = 2 * base1;
  const size_t base3 = base2 + (size_t)N;

  // staging geometry
  const int j0c = tid, j1c = tid + 512;
  const int r0 = j0c >> 6, k0b = (j0c & 63) << 4;
  const int r1 = j1c >> 6, k1b = (j1c & 63) << 4;
  char* d0h = sm + SM_HB + r0 * 1024 + (k0b ^ ((r0 & 7) << 4));
  char* d1h = sm + SM_HB + r1 * 1024 + (k1b ^ ((r1 & 7) << 4));
  char* d0t = sm + SM_T1 + r0 * 1024 + (k0b ^ ((r0 & 7) << 4));
  char* d1t = sm + SM_T1 + r1 * 1024 + (k1b ^ ((r1 & 7) << 4));
  char* d0s = sm + SM_TS + r0 * 1024 + (k0b ^ ((r0 & 7) << 4));
  char* d1s = sm + SM_TS + r1 * 1024 + (k1b ^ ((r1 & 7) << 4));

  // doP3(tt): p1/p2 (wave 0) + offsets (wave 1, rank 7); reads SM_T1/SM_TS
  auto doP3 = [&](int tt) {
    if (tt < 0) return;
    const int offs_t = offs_s[tt];
    if (w == 0) {
      s16x8 wo[16];
      const short* wb = Wo + (size_t)(rank * 16) * 512 + l * 8;
#pragma unroll
      for (int kc = 0; kc < 16; ++kc) wo[kc] = ld8(wb + (size_t)kc * 512);
      f32x4 acc = {0.f, 0.f, 0.f, 0.f};
      const char* ab = sm + (rank < 8 ? SM_T1 : SM_TS);
#pragma unroll
      for (int kc = 0; kc < 16; ++kc)
        acc = mfma16(ldA(ab, lr, kc * 64 + hi * 16), wo[kc], acc);
      const int nW = rank * 16 + lr;
      for (int r = 0; r < 4; r++) {
        int m = hi * 4 + r;
        if (tt < lens_s[m]) {
          size_t pos = (size_t)(offs_t + g * 16 + m);
          float v = acc[r] + bo_r;
          if (rank < 8) {
            out[pos * 128 + nW] = v;
            out[base3 + pos * 128 + nW] = v;
          } else {
            out[base1 + pos * 128 + (nW - 128)] = v;
          }
        }
      }
    } else if (w == 1 && rank == 7) {
      s16x8 wo[16];
      const short* wb = Wo + (size_t)(16 * 16) * 512 + l * 8;
#pragma unroll
      for (int kc = 0; kc < 16; ++kc) wo[kc] = ld8(wb + (size_t)kc * 512);
      f32x4 acc = {0.f, 0.f, 0.f, 0.f};
#pragma unroll
      for (int kc = 0; kc < 16; ++kc)
        acc = mfma16(ldA(sm + SM_TS, lr, kc * 64 + hi * 16), wo[kc], acc);
      if (lr == 0) {
        for (int r = 0; r < 4; r++) {
          int m = hi * 4 + r;
          if (tt < lens_s[m])
            out[base2 + (size_t)(offs_t + g * 16 + m)] = acc[r] + bo_r;
        }
      }
    }
  };

  // prologue: stage SM_HB = h0; SM_T1 = 0
  {
    const u64* hq = (const u64*)hb_;
    u64 a, b, c, d;
    ld4x8_issue(hq + 2 * j0c, hq + 2 * j0c + 1, hq + 2 * j1c, hq + 2 * j1c + 1,
                a, b, c, d);
    wait_vm4(a, b, c, d);
    *(u64*)d0h = a; *(u64*)(d0h + 8) = b;
    *(u64*)d1h = c; *(u64*)(d1h + 8) = d;
    *(u64*)d0t = 0ull; *(u64*)(d0t + 8) = 0ull;
    *(u64*)d1t = 0ull; *(u64*)(d1t + 8) = 0ull;
  }
  __syncthreads();
  f32x4 accP1 = {0.f, 0.f, 0.f, 0.f};
#pragma unroll
  for (int kc = 0; kc < 16; ++kc)
    accP1 = mfma16(ldA(sm + SM_HB, lr, kc * 64 + hi * 16), wgr[kc], accP1);

  for (int t = 0; t < steps; ++t) {
    const int bufp = (t & 1) ^ 1;  // write parity

    // ---- A: P1 finish (th1(t-1) half) -> gacc ----
    {
      f32x4 acc = accP1;
#pragma unroll
      for (int kc = 0; kc < 16; ++kc)
        acc = mfma16(ldA(sm + SM_T1, lr, kc * 64 + hi * 16), wgr[16 + kc], acc);
      for (int r = 0; r < 4; r++)
        gacc[(ga_w * 32 + j0_w * 16 + lr) * 17 + hi * 4 + r] = acc[r];
    }
    __syncthreads();  // S1

    // ---- B: cell + publish h (tid<256) ----
    if (tid < 256) {
      const int ua = 2 * p_c;
      const float* s0 = t ? bc0 : bn0;
      const float* s1 = t ? bc1 : bn1;
      float gi0 = gacc[(0 * 32 + ua) * 17 + m_c] + s0[0];
      float gf0 = gacc[(1 * 32 + ua) * 17 + m_c] + s0[1];
      float gg0 = gacc[(2 * 32 + ua) * 17 + m_c] + s0[2];
      float go0 = gacc[(3 * 32 + ua) * 17 + m_c] + s0[3];
      float gi1 = gacc[(0 * 32 + ua + 1) * 17 + m_c] + s1[0];
      float gf1 = gacc[(1 * 32 + ua + 1) * 17 + m_c] + s1[1];
      float gg1 = gacc[(2 * 32 + ua + 1) * 17 + m_c] + s1[2];
      float go1 = gacc[(3 * 32 + ua + 1) * 17 + m_c] + s1[3];
      float c0 = sigm(gf0) * creg0 + sigm(gi0) * tanhf(gg0);
      float c1 = sigm(gf1) * creg1 + sigm(gi1) * tanhf(gg1);
      creg0 = c0; creg1 = c1;
      float h0v = sigm(go0) * tanhf(c0);
      float h1v = sigm(go1) * tanhf(c1);
      u32 pk = (u32)f2bf(h0v) | ((u32)f2bf(h1v) << 16);
      u32_st((u32*)hb_ + bufp * 4096 + m_c * 256 + rank * 16 + p_c, pk);
    }
    DRAIN_VM;
    __syncthreads();  // S2: all h stores ACKed
    if (tid == 0) u32_st(hfl + rank, (u32)(t + 1));
    if (tid < 16) {
      int wd = 0;
      while ((int)flag_ld(hfl + tid) < t + 1 && ++wd < WDOG)
        __builtin_amdgcn_s_sleep(1);
    }
    __syncthreads();  // S3: h(t) visible group-wide

    // ---- C: stage h(t) (loads in flight while doP3(t-1) runs) ----
    {
      const u64* hq = (const u64*)hb_ + (size_t)bufp * 2048;
      u64 a, b, c, d;
      ld4x8_issue(hq + 2 * j0c, hq + 2 * j0c + 1, hq + 2 * j1c, hq + 2 * j1c + 1,
                  a, b, c, d);
      doP3(t - 1);
      wait_vm4(a, b, c, d);
      *(u64*)d0h = a; *(u64*)(d0h + 8) = b;
      *(u64*)d1h = c; *(u64*)(d1h + 8) = d;
    }
    __syncthreads();  // S4: SM_HB = h(t)

    // ---- D: P2 + publish th (w<6) ----
    if (w < 6) {
      f32x4 acc = {0.f, 0.f, 0.f, 0.f};
      const char* wl = sm + SM_WH + lt2 * 16384 + l * 16;
#pragma unroll
      for (int kc = 0; kc < 16; ++kc)
        acc = mfma16(ldA(sm + SM_HB, lr, kc * 64 + hi * 16),
                     *(const s16x8*)(wl + kc * 1024), acc);
      u32 my[4];
      for (int r = 0; r < 4; r++) my[r] = (u32)f2bf(tanhf(acc[r] + bh_r));
      u32 wordv[4];
      for (int r = 0; r < 4; r++) {
        u32 oth = (u32)__shfl_xor((int)my[r], 1, 64);
        wordv[r] = my[r] | (oth << 16);
      }
      if (!(l & 1)) {
        const int cp = lr >> 1;
        for (int r = 0; r < 4; r++) {
          int m = hi * 4 + r;
          u32* dst = (T2 < 32) ? (u32*)t1b + bufp * 4096 + m * 256 + T2 * 8 + cp
                   : (T2 < 64) ? (u32*)t2b + m * 256 + (T2 - 32) * 8 + cp
                               : (u32*)tob + m * 256 + (T2 - 64) * 8 + cp;
          u32_st(dst, wordv[r]);
        }
      }
    }
    DRAIN_VM;
    __syncthreads();  // S5: all th stores ACKed
    if (tid == 0) u32_st(tfl + rank, (u32)(t + 1));
    if (tid < 16) {
      int wd = 0;
      while ((int)flag_ld(tfl + tid) < t + 1 && ++wd < WDOG)
        __builtin_amdgcn_s_sleep(1);
    }
    __syncthreads();  // S6: th(t) visible group-wide

    // ---- E: stage th1(t) (+TS) with accP1 (h-half of t+1) hiding latency ----
    {
      const u64* tq = (const u64*)t1b + (size_t)bufp * 2048;
      u64 a, b, c, d, e = 0, f2 = 0, gq = 0, h2 = 0;
      ld4x8_issue(tq + 2 * j0c, tq + 2 * j0c + 1, tq + 2 * j1c, tq + 2 * j1c + 1,
                  a, b, c, d);
      if (rank >= 7) {
        const u64* sq = (const u64*)(rank == 7 ? tob : t2b);
        ld4x8_issue(sq + 2 * j0c, sq + 2 * j0c + 1, sq + 2 * j1c, sq + 2 * j1c + 1,
                    e, f2, gq, h2);
      }
      f32x4 ap = {0.f, 0.f, 0.f, 0.f};
#pragma unroll
      for (int kc = 0; kc < 16; ++kc)
        ap = mfma16(ldA(sm + SM_HB, lr, kc * 64 + hi * 16), wgr[kc], ap);
      accP1 = ap;
      wait_vm4(a, b, c, d);
      *(u64*)d0t = a; *(u64*)(d0t + 8) = b;
      *(u64*)d1t = c; *(u64*)(d1t + 8) = d;
      if (rank >= 7) {
        wait_vm4(e, f2, gq, h2);
        *(u64*)d0s = e; *(u64*)(d0s + 8) = f2;
        *(u64*)d1s = gq; *(u64*)(d1s + 8) = h2;
      }
    }
    __syncthreads();  // S7
  }
  doP3(steps - 1);
}

extern "C" void kernel_launch(void* const* d_in, const int* in_sizes, int n_in,
                              void* d_out, int out_size, void* d_ws, size_t ws_size,
                              hipStream_t stream) {
  const float* features = (const float*)d_in[0];
  const float* W_f2h = (const float*)d_in[1];
  const float* b_f2h = (const float*)d_in[2];
  const float* W_ih = (const float*)d_in[3];
  const float* W_hh = (const float*)d_in[4];
  const float* b_ih = (const float*)d_in[5];
  const float* b_hh = (const float*)d_in[6];
  const float* p1W1 = (const float*)d_in[7];
  const float* p1b1 = (const float*)d_in[8];
  const float* p1W2 = (const float*)d_in[9];
  const float* p1b2 = (const float*)d_in[10];
  const float* p2W1 = (const float*)d_in[11];
  const float* p2b1 = (const float*)d_in[12];
  const float* p2W2 = (const float*)d_in[13];
  const float* p2b2 = (const float*)d_in[14];
  const float* offW1 = (const float*)d_in[15];
  const float* offb1 = (const float*)d_in[16];
  const float* offW2 = (const float*)d_in[17];
  const float* offb2 = (const float*)d_in[18];
  const int* lens = (const int*)d_in[19];
  const int N = in_sizes[20];
  char* ws = (char*)d_ws;

  prep_w<<<1476, 256, 0, stream>>>(W_hh, W_ih, p1W2, p1W1, p2W1, offW1, p2W2, offW2, ws);
  prep_misc<<<34, 256, 0, stream>>>(b_ih, b_hh, W_ih, p1b2, p1b1, p2b1, offb1, p2b2,
                                    offb2, lens, ws);
  (void)hipFuncSetAttribute((const void*)rnn_main,
                            hipFuncAttributeMaxDynamicSharedMemorySize, SM_SZ);
  rnn_main<<<256, 512, SM_SZ, stream>>>(features, W_f2h, b_f2h, lens, ws,
                                        (float*)d_out, N);
}